// Round 1
// baseline (68.215 us; speedup 1.0000x reference)
//
#include <hip/hip_runtime.h>
#include <math.h>

#define BB 8
#define LX 128
#define LY 512
#define DD 256

// ws layout (floats): A[B*LX*D] at 0 ; Ct2[B][D/4][LY][4] at CT2_OFF
#define A_ELEMS (BB * LX * DD)   // 262144 floats
#define CT2_OFF A_ELEMS

// ---------------------------------------------------------------------------
// Kernel 1: fused GEMMs.
//   wgs 0..63   : A[r, :]   = x_row[r] @ W1[:D]  + b1      (row-major, r in [0,1024))
//   wgs 64..319 : Ct2[b][d/4][y][d%4] = (y_row @ W1[D:])   (d-quad packed transpose)
// Tile: 16 rows x 256 cols per wg, 256 threads, 4x4 register tile per thread.
// ---------------------------------------------------------------------------
__global__ __launch_bounds__(256) void gemm_kernel(
    const float* __restrict__ x, const float* __restrict__ y,
    const float* __restrict__ W1, const float* __restrict__ b1,
    float* __restrict__ ws)
{
    __shared__ float sA[32][20];    // [k][row] transposed input rows (pad 16->20)
    __shared__ float sW[32][256];   // [k][col]

    const int g  = blockIdx.x;
    const int t  = threadIdx.x;
    const int tc = t & 63;          // cols 4tc..4tc+3
    const int tr = t >> 6;          // rows 4tr..4tr+3

    const bool isA = (g < 64);
    const float* inp;
    const float* wbase;
    int row0;
    if (isA) { row0 = g * 16;        inp = x; wbase = W1; }
    else     { row0 = (g - 64) * 16; inp = y; wbase = W1 + DD * DD; }

    float acc[4][4];
    #pragma unroll
    for (int i = 0; i < 4; ++i)
        #pragma unroll
        for (int j = 0; j < 4; ++j) acc[i][j] = 0.f;

    for (int k0 = 0; k0 < DD; k0 += 32) {
        __syncthreads();
        if (t < 128) {                       // stage 16x32 input block, transposed
            int row = t >> 3, kq = t & 7;
            const float4 v = *(const float4*)(inp + (size_t)(row0 + row) * DD + k0 + 4 * kq);
            sA[4*kq + 0][row] = v.x;
            sA[4*kq + 1][row] = v.y;
            sA[4*kq + 2][row] = v.z;
            sA[4*kq + 3][row] = v.w;
        }
        #pragma unroll
        for (int i = 0; i < 8; ++i) {        // stage 32x256 W block
            int flat = t + i * 256;          // float4 index over [32][64]
            int kk = flat >> 6, c4 = flat & 63;
            *(float4*)&sW[kk][4*c4] = *(const float4*)(wbase + (size_t)(k0 + kk) * DD + 4 * c4);
        }
        __syncthreads();
        #pragma unroll
        for (int k = 0; k < 32; ++k) {
            const float4 a4 = *(const float4*)&sA[k][4*tr];  // broadcast within wave
            const float4 w4 = *(const float4*)&sW[k][4*tc];
            const float a[4] = {a4.x, a4.y, a4.z, a4.w};
            const float w[4] = {w4.x, w4.y, w4.z, w4.w};
            #pragma unroll
            for (int i = 0; i < 4; ++i)
                #pragma unroll
                for (int j = 0; j < 4; ++j)
                    acc[i][j] = fmaf(a[i], w[j], acc[i][j]);
        }
    }

    if (isA) {
        const float4 bv = *(const float4*)(b1 + 4 * tc);
        #pragma unroll
        for (int i = 0; i < 4; ++i) {
            const int r = row0 + 4 * tr + i;            // global x row [0,1024)
            float4 o;
            o.x = acc[i][0] + bv.x; o.y = acc[i][1] + bv.y;
            o.z = acc[i][2] + bv.z; o.w = acc[i][3] + bv.w;
            *(float4*)(ws + (size_t)r * DD + 4 * tc) = o;
        }
    } else {
        #pragma unroll
        for (int i = 0; i < 4; ++i) {
            const int ry = row0 + 4 * tr + i;           // [0,4096)
            const int bb = ry >> 9, yy = ry & 511;
            float4 o = {acc[i][0], acc[i][1], acc[i][2], acc[i][3]};
            // Ct2[bb][tc][yy][0..3]  (float4 index (bb*64+tc)*512+yy)
            *(float4*)(ws + CT2_OFF + (((size_t)(bb * 64 + tc) * 512 + yy) << 2)) = o;
        }
    }
}

// ---------------------------------------------------------------------------
// Kernel 2: per (b, 4-x-block): scores + mask + softmax + context.
// grid 256 (b = blockIdx&7 for XCD L2 locality), 256 threads.
// ---------------------------------------------------------------------------
__global__ __launch_bounds__(256) void attn_kernel(
    const float* __restrict__ yin, const int* __restrict__ ymask,
    const float* __restrict__ W2, const float* __restrict__ b2,
    const float* __restrict__ ws, float* __restrict__ out)
{
    __shared__ float sa[4][DD];     // a = hx + b1 for the 4 x rows
    __shared__ float sw2[DD];
    __shared__ float sc[4][LY];     // scores -> weights

    const int t  = threadIdx.x;
    const int b  = blockIdx.x & 7;
    const int xb = blockIdx.x >> 3;

    {   // load a rows (A from ws)
        const int xi = t >> 6, d4 = t & 63;
        *(float4*)&sa[xi][4*d4] =
            *(const float4*)(ws + (size_t)(b * LX + xb * 4 + xi) * DD + 4 * d4);
    }
    if (t < 64) *(float4*)&sw2[4*t] = *(const float4*)(W2 + 4 * t);
    const float b2v = b2[0];
    __syncthreads();

    // ---- phase 1: scores for y0 = t, y1 = t+256 --------------------------
    const int y0 = t, y1 = t + 256;
    float s0[4] = {0.f, 0.f, 0.f, 0.f};
    float s1[4] = {0.f, 0.f, 0.f, 0.f};
    const float4* ct = (const float4*)(ws + CT2_OFF) + (size_t)b * 64 * 512;

    #pragma unroll 4
    for (int dq = 0; dq < 64; ++dq) {
        const float4 c0 = ct[dq * 512 + y0];
        const float4 c1 = ct[dq * 512 + y1];
        const float4 w4 = *(const float4*)&sw2[4*dq];
        #pragma unroll
        for (int xi = 0; xi < 4; ++xi) {
            const float4 av = *(const float4*)&sa[xi][4*dq];   // wave-broadcast
            s0[xi] = fmaf(fmaxf(av.x + c0.x, 0.f), w4.x, s0[xi]);
            s0[xi] = fmaf(fmaxf(av.y + c0.y, 0.f), w4.y, s0[xi]);
            s0[xi] = fmaf(fmaxf(av.z + c0.z, 0.f), w4.z, s0[xi]);
            s0[xi] = fmaf(fmaxf(av.w + c0.w, 0.f), w4.w, s0[xi]);
            s1[xi] = fmaf(fmaxf(av.x + c1.x, 0.f), w4.x, s1[xi]);
            s1[xi] = fmaf(fmaxf(av.y + c1.y, 0.f), w4.y, s1[xi]);
            s1[xi] = fmaf(fmaxf(av.z + c1.z, 0.f), w4.z, s1[xi]);
            s1[xi] = fmaf(fmaxf(av.w + c1.w, 0.f), w4.w, s1[xi]);
        }
    }
    const int m0 = ymask[b * LY + y0];
    const int m1 = ymask[b * LY + y1];
    #pragma unroll
    for (int xi = 0; xi < 4; ++xi) {
        sc[xi][y0] = m0 ? -1e30f : (s0[xi] + b2v);
        sc[xi][y1] = m1 ? -1e30f : (s1[xi] + b2v);
    }
    __syncthreads();

    // ---- phase 2: softmax over y (wave w handles row xi=w) ---------------
    {
        const int xi = t >> 6, l = t & 63;
        float v[8];
        float m = -3.4e38f;
        #pragma unroll
        for (int k = 0; k < 8; ++k) { v[k] = sc[xi][l + 64 * k]; m = fmaxf(m, v[k]); }
        #pragma unroll
        for (int off = 32; off; off >>= 1) m = fmaxf(m, __shfl_xor(m, off));
        float s = 0.f;
        #pragma unroll
        for (int k = 0; k < 8; ++k) { v[k] = expf(v[k] - m); s += v[k]; }
        #pragma unroll
        for (int off = 32; off; off >>= 1) s += __shfl_xor(s, off);
        const float inv = 1.f / s;
        #pragma unroll
        for (int k = 0; k < 8; ++k) sc[xi][l + 64 * k] = v[k] * inv;
    }
    __syncthreads();

    // ---- phase 3: contexts[xi][d=t] = sum_y w[xi][y] * y[b][y][t] --------
    float acc[4] = {0.f, 0.f, 0.f, 0.f};
    const float* yb = yin + (size_t)b * LY * DD;
    #pragma unroll 2
    for (int yq = 0; yq < 128; ++yq) {
        const float v0 = yb[(size_t)(4 * yq + 0) * DD + t];
        const float v1 = yb[(size_t)(4 * yq + 1) * DD + t];
        const float v2 = yb[(size_t)(4 * yq + 2) * DD + t];
        const float v3 = yb[(size_t)(4 * yq + 3) * DD + t];
        #pragma unroll
        for (int xi = 0; xi < 4; ++xi) {
            const float4 wv = *(const float4*)&sc[xi][4 * yq];  // wave-broadcast
            acc[xi] = fmaf(wv.x, v0, acc[xi]);
            acc[xi] = fmaf(wv.y, v1, acc[xi]);
            acc[xi] = fmaf(wv.z, v2, acc[xi]);
            acc[xi] = fmaf(wv.w, v3, acc[xi]);
        }
    }
    #pragma unroll
    for (int xi = 0; xi < 4; ++xi)
        out[(size_t)(b * LX + xb * 4 + xi) * DD + t] = acc[xi];
}

// ---------------------------------------------------------------------------
extern "C" void kernel_launch(void* const* d_in, const int* in_sizes, int n_in,
                              void* d_out, int out_size, void* d_ws, size_t ws_size,
                              hipStream_t stream) {
    const float* x     = (const float*)d_in[0];
    const float* y     = (const float*)d_in[1];
    const int*   ymask = (const int*)  d_in[2];
    const float* W1    = (const float*)d_in[3];
    const float* b1    = (const float*)d_in[4];
    const float* W2    = (const float*)d_in[5];
    const float* b2    = (const float*)d_in[6];
    float* ws  = (float*)d_ws;
    float* out = (float*)d_out;

    hipLaunchKernelGGL(gemm_kernel, dim3(320), dim3(256), 0, stream, x, y, W1, b1, ws);
    hipLaunchKernelGGL(attn_kernel, dim3(256), dim3(256), 0, stream, y, ymask, W2, b2, ws, out);
}

// Round 2
// 48.366 us; speedup vs baseline: 1.4104x; 1.4104x over previous
//
#include <hip/hip_runtime.h>
#include <math.h>

#define BB 8
#define LX 128
#define LY 512
#define DD 256

// ws layout (floats):
//   A   [B][LX][D]                      @ 0
//   Ct2 [B][D/4][LY][4]                 @ CT2_OFF
//   part[B][16][8][8][D]  (xg,yc,xi)    @ PART_OFF
//   pml [B*16*8][8][2]    (m,l)         @ PML_OFF
#define A_ELEMS   (BB * LX * DD)                  // 262144
#define CT2_OFF   A_ELEMS
#define CT2_ELEMS (BB * (DD / 4) * LY * 4)        // 1048576
#define PART_OFF  (CT2_OFF + CT2_ELEMS)           // 1310720
#define PART_ELEMS (BB * 16 * 8 * 8 * DD)         // 2097152
#define PML_OFF   (PART_OFF + PART_ELEMS)         // 3407872

// ---------------------------------------------------------------------------
// Kernel 1: fused GEMMs, 16x128 tiles, grid 640.
//   wgs 0..127   : A[r, cols] = x_row @ W1[:D] + b1
//   wgs 128..639 : Ct2[b][d/4][y][d%4] = y_row @ W1[D:]
// ---------------------------------------------------------------------------
__global__ __launch_bounds__(256) void gemm_kernel(
    const float* __restrict__ x, const float* __restrict__ y,
    const float* __restrict__ W1, const float* __restrict__ b1,
    float* __restrict__ ws)
{
    __shared__ float sA[32][20];    // [k][row], 16 rows padded
    __shared__ float sW[32][128];   // [k][col]

    const int g  = blockIdx.x;
    const int t  = threadIdx.x;
    const int tc = t & 31;          // cols col0 + 4tc .. +3
    const int tr = t >> 5;          // rows 2tr, 2tr+1

    const bool isA = (g < 128);
    const float* inp;
    const float* wbase;
    int row0, col0;
    if (isA) { col0 = (g & 1) * 128;        row0 = (g >> 1) * 16;        inp = x; wbase = W1; }
    else     { col0 = ((g - 128) & 1) * 128; row0 = ((g - 128) >> 1) * 16; inp = y; wbase = W1 + DD * DD; }

    float acc[2][4];
    #pragma unroll
    for (int i = 0; i < 2; ++i)
        #pragma unroll
        for (int j = 0; j < 4; ++j) acc[i][j] = 0.f;

    for (int k0 = 0; k0 < DD; k0 += 32) {
        __syncthreads();
        if (t < 128) {                       // stage 16x32 input block, transposed
            int row = t >> 3, kq = t & 7;
            const float4 v = *(const float4*)(inp + (size_t)(row0 + row) * DD + k0 + 4 * kq);
            sA[4*kq + 0][row] = v.x;
            sA[4*kq + 1][row] = v.y;
            sA[4*kq + 2][row] = v.z;
            sA[4*kq + 3][row] = v.w;
        }
        #pragma unroll
        for (int i = 0; i < 4; ++i) {        // stage 32x128 W block
            int flat = t + i * 256;          // float4 index over [32][32]
            int kk = flat >> 5, c4 = flat & 31;
            *(float4*)&sW[kk][4*c4] = *(const float4*)(wbase + (size_t)(k0 + kk) * DD + col0 + 4 * c4);
        }
        __syncthreads();
        #pragma unroll
        for (int k = 0; k < 32; ++k) {
            const float a0 = sA[k][2*tr], a1 = sA[k][2*tr + 1];
            const float4 w4 = *(const float4*)&sW[k][4*tc];
            acc[0][0] = fmaf(a0, w4.x, acc[0][0]);
            acc[0][1] = fmaf(a0, w4.y, acc[0][1]);
            acc[0][2] = fmaf(a0, w4.z, acc[0][2]);
            acc[0][3] = fmaf(a0, w4.w, acc[0][3]);
            acc[1][0] = fmaf(a1, w4.x, acc[1][0]);
            acc[1][1] = fmaf(a1, w4.y, acc[1][1]);
            acc[1][2] = fmaf(a1, w4.z, acc[1][2]);
            acc[1][3] = fmaf(a1, w4.w, acc[1][3]);
        }
    }

    if (isA) {
        const float4 bv = *(const float4*)(b1 + col0 + 4 * tc);
        #pragma unroll
        for (int i = 0; i < 2; ++i) {
            const int r = row0 + 2 * tr + i;
            float4 o;
            o.x = acc[i][0] + bv.x; o.y = acc[i][1] + bv.y;
            o.z = acc[i][2] + bv.z; o.w = acc[i][3] + bv.w;
            *(float4*)(ws + (size_t)r * DD + col0 + 4 * tc) = o;
        }
    } else {
        const int dq = (col0 >> 2) + tc;
        #pragma unroll
        for (int i = 0; i < 2; ++i) {
            const int ry = row0 + 2 * tr + i;           // [0,4096)
            const int bb = ry >> 9, yy = ry & 511;
            float4 o = {acc[i][0], acc[i][1], acc[i][2], acc[i][3]};
            *(float4*)(ws + CT2_OFF + (((size_t)(bb * 64 + dq) * 512 + yy) << 2)) = o;
        }
    }
}

// ---------------------------------------------------------------------------
// Kernel 2: flash-style partial attention.
// grid 1024 = (b=bid&7) x (xg: 8 x-rows) x (yc: 64-y chunk). 256 threads.
// ---------------------------------------------------------------------------
__global__ __launch_bounds__(256, 4) void score_kernel(
    const float* __restrict__ yin, const int* __restrict__ ymask,
    const float* __restrict__ W2, const float* __restrict__ b2,
    float* __restrict__ ws)
{
    __shared__ float sa[8][DD];     // a = hx + b1 for the 8 x rows (8KB)
    __shared__ float sw2[DD];       // 1KB
    __shared__ float sp[8][64];     // p values (2KB)
    __shared__ float sm[8], sl[8];

    const int t  = threadIdx.x;
    const int b  = blockIdx.x & 7;
    const int r  = blockIdx.x >> 3;     // [0,128)
    const int xg = r & 15;
    const int yc = r >> 4;

    {   // A rows are contiguous: 2048 floats
        const float4* src = (const float4*)(ws + (size_t)(b * LX + xg * 8) * DD);
        ((float4*)sa)[t]       = src[t];
        ((float4*)sa)[t + 256] = src[t + 256];
    }
    if (t < 64) *(float4*)&sw2[4*t] = *(const float4*)(W2 + 4 * t);
    const float b2v = b2[0];
    __syncthreads();

    // ---- scores: wave w handles x rows 2w,2w+1; lane = y within chunk ----
    const int lane = t & 63;
    const int xh   = t >> 6;
    const int xi0  = 2 * xh, xi1 = 2 * xh + 1;
    const int y    = yc * 64 + lane;

    float s0a = 0.f, s0b = 0.f, s1a = 0.f, s1b = 0.f;
    const float4* ct = (const float4*)(ws + CT2_OFF) + ((size_t)b * 64) * 512 + y;

    #pragma unroll 4
    for (int dq = 0; dq < 64; ++dq) {
        const float4 c  = ct[dq * 512];
        const float4 w4 = *(const float4*)&sw2[4*dq];
        const float4 a0 = *(const float4*)&sa[xi0][4*dq];
        const float4 a1 = *(const float4*)&sa[xi1][4*dq];
        s0a = fmaf(fmaxf(a0.x + c.x, 0.f), w4.x, s0a);
        s0b = fmaf(fmaxf(a0.y + c.y, 0.f), w4.y, s0b);
        s0a = fmaf(fmaxf(a0.z + c.z, 0.f), w4.z, s0a);
        s0b = fmaf(fmaxf(a0.w + c.w, 0.f), w4.w, s0b);
        s1a = fmaf(fmaxf(a1.x + c.x, 0.f), w4.x, s1a);
        s1b = fmaf(fmaxf(a1.y + c.y, 0.f), w4.y, s1b);
        s1a = fmaf(fmaxf(a1.z + c.z, 0.f), w4.z, s1a);
        s1b = fmaf(fmaxf(a1.w + c.w, 0.f), w4.w, s1b);
    }
    const bool msk = ymask[b * LY + y] != 0;
    const float sc0 = msk ? -1e30f : (s0a + s0b + b2v);
    const float sc1 = msk ? -1e30f : (s1a + s1b + b2v);

    float m0 = sc0, m1 = sc1;
    #pragma unroll
    for (int off = 32; off; off >>= 1) {
        m0 = fmaxf(m0, __shfl_xor(m0, off));
        m1 = fmaxf(m1, __shfl_xor(m1, off));
    }
    const float p0 = msk ? 0.f : expf(sc0 - m0);
    const float p1 = msk ? 0.f : expf(sc1 - m1);
    float l0 = p0, l1 = p1;
    #pragma unroll
    for (int off = 32; off; off >>= 1) {
        l0 += __shfl_xor(l0, off);
        l1 += __shfl_xor(l1, off);
    }
    sp[xi0][lane] = p0;
    sp[xi1][lane] = p1;
    if (lane == 0) { sm[xi0] = m0; sm[xi1] = m1; sl[xi0] = l0; sl[xi1] = l1; }
    __syncthreads();

    // ---- partial context: thread owns d = t ------------------------------
    float acc[8] = {0.f, 0.f, 0.f, 0.f, 0.f, 0.f, 0.f, 0.f};
    const float* yb = yin + ((size_t)b * LY + yc * 64) * DD;
    #pragma unroll 4
    for (int yy = 0; yy < 64; ++yy) {
        const float v = yb[(size_t)yy * DD + t];
        #pragma unroll
        for (int xi = 0; xi < 8; ++xi) acc[xi] = fmaf(sp[xi][yy], v, acc[xi]);
    }

    float* pb = ws + PART_OFF + (((size_t)(b * 16 + xg) * 8 + yc) * 8) * DD;
    #pragma unroll
    for (int xi = 0; xi < 8; ++xi) pb[xi * DD + t] = acc[xi];
    if (t < 8) {
        float* ml = ws + PML_OFF + ((size_t)(b * 16 + xg) * 8 + yc) * 16;
        ml[2 * t]     = sm[t];
        ml[2 * t + 1] = sl[t];
    }
}

// ---------------------------------------------------------------------------
// Kernel 3: combine the 8 y-chunk partials per (b, x) row. grid 1024.
// ---------------------------------------------------------------------------
__global__ __launch_bounds__(256) void combine_kernel(
    const float* __restrict__ ws, float* __restrict__ out)
{
    const int t = threadIdx.x;
    const int b = blockIdx.x & 7;
    const int x = blockIdx.x >> 3;      // [0,128)
    const int xg = x >> 3, xi = x & 7;

    float mv[8], lv[8];
    float M = -3.4e38f;
    #pragma unroll
    for (int c = 0; c < 8; ++c) {
        const float* ml = ws + PML_OFF + ((size_t)(b * 16 + xg) * 8 + c) * 16;
        mv[c] = ml[2 * xi];
        lv[c] = ml[2 * xi + 1];
        M = fmaxf(M, mv[c]);
    }
    float L = 0.f, scl[8];
    #pragma unroll
    for (int c = 0; c < 8; ++c) { scl[c] = expf(mv[c] - M); L = fmaf(scl[c], lv[c], L); }

    float acc = 0.f;
    #pragma unroll
    for (int c = 0; c < 8; ++c) {
        const float* pb = ws + PART_OFF + (((size_t)(b * 16 + xg) * 8 + c) * 8 + xi) * DD;
        acc = fmaf(scl[c], pb[t], acc);
    }
    out[((size_t)(b * LX + x)) * DD + t] = acc / L;
}

// ---------------------------------------------------------------------------
extern "C" void kernel_launch(void* const* d_in, const int* in_sizes, int n_in,
                              void* d_out, int out_size, void* d_ws, size_t ws_size,
                              hipStream_t stream) {
    const float* x     = (const float*)d_in[0];
    const float* y     = (const float*)d_in[1];
    const int*   ymask = (const int*)  d_in[2];
    const float* W1    = (const float*)d_in[3];
    const float* b1    = (const float*)d_in[4];
    const float* W2    = (const float*)d_in[5];
    const float* b2    = (const float*)d_in[6];
    float* ws  = (float*)d_ws;
    float* out = (float*)d_out;

    hipLaunchKernelGGL(gemm_kernel, dim3(640), dim3(256), 0, stream, x, y, W1, b1, ws);
    hipLaunchKernelGGL(score_kernel, dim3(1024), dim3(256), 0, stream, y, ymask, W2, b2, ws);
    hipLaunchKernelGGL(combine_kernel, dim3(1024), dim3(256), 0, stream, ws, out);
}